// Round 8
// baseline (571.249 us; speedup 1.0000x reference)
//
#include <hip/hip_runtime.h>

// TTRFluxLayer R10: phi split into two weight-resident streaming GEMMs.
// Learned R7/R9: per-wave weights-from-global is latency-bound (~166us) and hipcc
// collapses source-level reg pipelines (VGPR=56 proves loads re-sunk). R4-style
// per-tile weight staging wastes 300MB of staging traffic. Fix: amortize.
//  k1a gemm1: w1 (68K) in LDS once per block; 6x128-row x tiles double-buffered
//             (prefetch to regs after barrier, LDS-write after compute);
//             SiLU; h (fp16) written to global. 1 barrier/iter.
//  k1b gemm2: w2 (135K) in LDS once; NO loop barriers — waves free-run streaming
//             h rows from global (L2/L3-hot), avA/avB named rotation; qp/kp out.
//  h (100.66MB) exactly aliases Wf+S regions (2*SZ; dead until s_kernel).
// k0 prep / k0b vt / k2 s (kp LDS-transpose) / k3 pfx / k4 scan: unchanged.
// ws: w1h 64K | w2h 128K | qp 48M | kp 48M | Wf/h 48M | S/Wr/h 48M | vT 24M

typedef __attribute__((ext_vector_type(8))) _Float16 f16x8;
typedef __attribute__((ext_vector_type(4))) _Float16 f16x4;
typedef __attribute__((ext_vector_type(4))) float f32x4;

#define MFMA16(a, b, c) __builtin_amdgcn_mfma_f32_16x16x32_f16((a), (b), (c), 0, 0, 0)

constexpr int BH   = 24;
constexpr int NSEQ = 4096;
constexpr int DD   = 128;
constexpr int FF   = 256;
constexpr int CHK  = 128;
constexpr int NC   = NSEQ / CHK;     // 32
constexpr int NROWS = BH * NSEQ;     // 98304 (per q or k); unified R-space = 2*NROWS

// ---------------- k0: weight convert ----------------
__global__ void prep_kernel(const float* __restrict__ w1, const float* __restrict__ w2,
                            _Float16* __restrict__ w1h, _Float16* __restrict__ w2h) {
  int i = blockIdx.x * 256 + threadIdx.x;
  if (i < FF * DD) w1h[i] = (_Float16)w1[i];
  if (i < FF * FF) w2h[i] = (_Float16)w2[i];
}

// ---------------- k0b: v -> vT fp16 [bh][d][s] ----------------
__global__ void vt_kernel(const float* __restrict__ v, _Float16* __restrict__ vT) {
  __shared__ __align__(16) _Float16 lt[128][136];
  int blk = blockIdx.x;
  int c = blk & 31, bh = blk >> 5;
  const float* vc = v + ((size_t)bh * NSEQ + c * CHK) * DD;
  int tid = threadIdx.x;
#pragma unroll
  for (int it = 0; it < 16; ++it) {
    int flat = it * 1024 + tid * 4;  // 128s x 128d
    int s = flat >> 7, d0 = flat & 127;
    float4 xv = *(const float4*)&vc[(size_t)s * DD + d0];
    lt[d0 + 0][s] = (_Float16)xv.x;
    lt[d0 + 1][s] = (_Float16)xv.y;
    lt[d0 + 2][s] = (_Float16)xv.z;
    lt[d0 + 3][s] = (_Float16)xv.w;
  }
  __syncthreads();
#pragma unroll
  for (int it = 0; it < 8; ++it) {
    int flat = it * 256 + tid;  // 128d x 16 s-groups
    int d = flat >> 4, sg = flat & 15;
    *(f16x8*)&vT[((size_t)bh * DD + d) * NSEQ + c * CHK + sg * 8] =
        *(const f16x8*)&lt[d][sg * 8];
  }
}

// ---------------- k1a: GEMM1 + SiLU -> h (w1 LDS-resident, x dbuf) ----------
__global__ __launch_bounds__(1024, 4)
void gemm1_kernel(const float* __restrict__ q, const float* __restrict__ k,
                  const float* __restrict__ b1, const _Float16* __restrict__ w1h,
                  _Float16* __restrict__ h) {
  __shared__ __align__(16) _Float16 w1s[256][136];     // 69632 B
  __shared__ __align__(16) _Float16 xs[2][128][136];   // 2 x 34816 B
  int tid = threadIdx.x;
  int lane = tid & 63, wv = tid >> 6, lr = lane & 15, lq = lane >> 4;
  int wm = wv & 3, wn = wv >> 2;  // 4 row-strips(32) x 4 F-strips(64)
  int blk = blockIdx.x;           // 256 blocks; rows [blk*768, blk*768+768)
  const float* srcb = (blk < 128) ? q + (size_t)blk * 768 * DD
                                  : k + (size_t)(blk - 128) * 768 * DD;
  _Float16* hb = h + (size_t)blk * 768 * FF;

  // stage w1 once (256x128 f16)
#pragma unroll
  for (int it = 0; it < 4; ++it) {
    int flat = it * 1024 + tid;
    int f = flat >> 4, cg = flat & 15;
    *(f16x8*)&w1s[f][cg * 8] = *(const f16x8*)&w1h[f * DD + cg * 8];
  }
  // stage x tile 0
#pragma unroll
  for (int it = 0; it < 4; ++it) {
    int flat = it * 1024 + tid;
    int r = flat >> 5, dg = flat & 31;
    float4 xv = *(const float4*)&srcb[(size_t)r * DD + dg * 4];
    f16x4 hv = {(_Float16)xv.x, (_Float16)xv.y, (_Float16)xv.z, (_Float16)xv.w};
    *(f16x4*)&xs[0][r][dg * 4] = hv;
  }
  float bb1[4];
#pragma unroll
  for (int fn = 0; fn < 4; ++fn) bb1[fn] = b1[wn * 64 + fn * 16 + lr];

  for (int t = 0; t < 6; ++t) {
    int cur = t & 1;
    __syncthreads();  // staging of xs[cur] visible; prior reads of xs[cur^1] done

    // issue next tile's global loads now (consumed ~end of iter)
    float4 rx0, rx1, rx2, rx3;
    if (t < 5) {
      const float* nsrc = srcb + (size_t)(t + 1) * 128 * DD;
      {int flat = 0 * 1024 + tid; rx0 = *(const float4*)&nsrc[(size_t)(flat >> 5) * DD + (flat & 31) * 4];}
      {int flat = 1 * 1024 + tid; rx1 = *(const float4*)&nsrc[(size_t)(flat >> 5) * DD + (flat & 31) * 4];}
      {int flat = 2 * 1024 + tid; rx2 = *(const float4*)&nsrc[(size_t)(flat >> 5) * DD + (flat & 31) * 4];}
      {int flat = 3 * 1024 + tid; rx3 = *(const float4*)&nsrc[(size_t)(flat >> 5) * DD + (flat & 31) * 4];}
    }

    // GEMM1: wave tile 32x64, K=128, all operands LDS
    f32x4 acc[2][4] = {};
#pragma unroll
    for (int ks = 0; ks < 4; ++ks) {
      f16x8 av[2];
#pragma unroll
      for (int im = 0; im < 2; ++im)
        av[im] = *(const f16x8*)&xs[cur][wm * 32 + im * 16 + lr][ks * 32 + lq * 8];
#pragma unroll
      for (int fn = 0; fn < 4; ++fn) {
        f16x8 bv = *(const f16x8*)&w1s[wn * 64 + fn * 16 + lr][ks * 32 + lq * 8];
#pragma unroll
        for (int im = 0; im < 2; ++im) acc[im][fn] = MFMA16(av[im], bv, acc[im][fn]);
      }
    }

    // SiLU + h store (scalar f16: per-instr 4 rows x 32B contiguous segments)
    _Float16* ht = hb + (size_t)t * 128 * FF;
#pragma unroll
    for (int im = 0; im < 2; ++im)
#pragma unroll
      for (int fn = 0; fn < 4; ++fn) {
        int g = wn * 64 + fn * 16 + lr;
        int r0 = wm * 32 + im * 16 + lq * 4;
#pragma unroll
        for (int r = 0; r < 4; ++r) {
          float xv = acc[im][fn][r] + bb1[fn];
          ht[(size_t)(r0 + r) * FF + g] = (_Float16)(xv * __builtin_amdgcn_rcpf(1.0f + __expf(-xv)));
        }
      }

    // write prefetched tile into the other buffer (hazard cleared by this iter's barrier)
    if (t < 5) {
      int nxt = cur ^ 1;
      {int flat = 0 * 1024 + tid; f16x4 hv = {(_Float16)rx0.x, (_Float16)rx0.y, (_Float16)rx0.z, (_Float16)rx0.w};
       *(f16x4*)&xs[nxt][flat >> 5][(flat & 31) * 4] = hv;}
      {int flat = 1 * 1024 + tid; f16x4 hv = {(_Float16)rx1.x, (_Float16)rx1.y, (_Float16)rx1.z, (_Float16)rx1.w};
       *(f16x4*)&xs[nxt][flat >> 5][(flat & 31) * 4] = hv;}
      {int flat = 2 * 1024 + tid; f16x4 hv = {(_Float16)rx2.x, (_Float16)rx2.y, (_Float16)rx2.z, (_Float16)rx2.w};
       *(f16x4*)&xs[nxt][flat >> 5][(flat & 31) * 4] = hv;}
      {int flat = 3 * 1024 + tid; f16x4 hv = {(_Float16)rx3.x, (_Float16)rx3.y, (_Float16)rx3.z, (_Float16)rx3.w};
       *(f16x4*)&xs[nxt][flat >> 5][(flat & 31) * 4] = hv;}
    }
  }
}

// ---------------- k1b: GEMM2 -> qp/kp (w2 LDS-resident, barrier-free loop) ----
__global__ __launch_bounds__(1024, 4)
void gemm2_kernel(const _Float16* __restrict__ h, const float* __restrict__ b2,
                  const _Float16* __restrict__ w2h,
                  _Float16* __restrict__ qp, _Float16* __restrict__ kp) {
  __shared__ __align__(16) _Float16 w2s[256][264];  // 135168 B
  int tid = threadIdx.x;
  int lane = tid & 63, wv = tid >> 6, lr = lane & 15, lq = lane >> 4;
  int wm = wv & 3, wn = wv >> 2;  // 4 row-strips(32) x 4 G-strips(64)
  int blk = blockIdx.x;           // 256 blocks; rows [blk*768, blk*768+768)
  const _Float16* hb = h + (size_t)blk * 768 * FF;
  _Float16* dstb = (blk < 128) ? qp + (size_t)blk * 768 * FF
                               : kp + (size_t)(blk - 128) * 768 * FF;

  // stage w2 once (256x256 f16)
#pragma unroll
  for (int it = 0; it < 8; ++it) {
    int flat = it * 1024 + tid;
    int g = flat >> 5, cg = flat & 31;
    *(f16x8*)&w2s[g][cg * 8] = *(const f16x8*)&w2h[(size_t)g * FF + cg * 8];
  }
  float bb2[4];
#pragma unroll
  for (int fn = 0; fn < 4; ++fn) bb2[fn] = b2[wn * 64 + fn * 16 + lr];
  __syncthreads();  // the only barrier

  auto loadA = [&](f16x8* av, int t, int im) {
    const _Float16* p = hb + (size_t)(t * 128 + wm * 32 + im * 16 + lr) * FF + lq * 8;
#pragma unroll
    for (int ks = 0; ks < 8; ++ks) av[ks] = *(const f16x8*)&p[ks * 32];
  };

  f16x8 avA[8], avB[8];
  loadA(avA, 0, 0);
  for (int t = 0; t < 6; ++t) {
    f32x4 acc[2][4] = {};
    loadA(avB, t, 1);  // in flight under im=0 MFMAs
#pragma unroll
    for (int ks = 0; ks < 8; ++ks)
#pragma unroll
      for (int fn = 0; fn < 4; ++fn) {
        f16x8 bv = *(const f16x8*)&w2s[wn * 64 + fn * 16 + lr][ks * 32 + lq * 8];
        acc[0][fn] = MFMA16(avA[ks], bv, acc[0][fn]);
      }
    if (t < 5) loadA(avA, t + 1, 0);  // in flight under im=1 MFMAs + epilogue
#pragma unroll
    for (int ks = 0; ks < 8; ++ks)
#pragma unroll
      for (int fn = 0; fn < 4; ++fn) {
        f16x8 bv = *(const f16x8*)&w2s[wn * 64 + fn * 16 + lr][ks * 32 + lq * 8];
        acc[1][fn] = MFMA16(avB[ks], bv, acc[1][fn]);
      }
    // epilogue (scalar f16: per-instr 4 rows x 32B segments)
#pragma unroll
    for (int im = 0; im < 2; ++im)
#pragma unroll
      for (int fn = 0; fn < 4; ++fn) {
        int g = wn * 64 + fn * 16 + lr;
        int r0 = t * 128 + wm * 32 + im * 16 + lq * 4;
#pragma unroll
        for (int r = 0; r < 4; ++r)
          dstb[(size_t)(r0 + r) * FF + g] = (_Float16)(acc[im][fn][r] + bb2[fn]);
      }
  }
}

// ---------------- k2: S^T[d][f] per chunk (kp transposed in LDS) ----------------
__global__ __launch_bounds__(512, 2)
void s_kernel(const _Float16* __restrict__ vT, const _Float16* __restrict__ kp,
              _Float16* __restrict__ S) {
  __shared__ __align__(16) _Float16 vt[128][136];
  __shared__ __align__(16) _Float16 kt[256][136];  // kt[f][s ^ swz(f)]
  int blk = blockIdx.x;
  int c = blk & 31, bh = blk >> 5;
  int tid = threadIdx.x;
#pragma unroll
  for (int it = 0; it < 4; ++it) {
    int flat = it * 512 + tid;
    int d = flat >> 4, sg = flat & 15;
    *(f16x8*)&vt[d][sg * 8] = *(const f16x8*)&vT[((size_t)bh * DD + d) * NSEQ + c * CHK + sg * 8];
  }
#pragma unroll
  for (int it = 0; it < 8; ++it) {
    int flat = it * 512 + tid;  // 128 s x 32 f-groups
    int s = flat >> 5, fg = flat & 31;
    f16x8 kv = *(const f16x8*)&kp[((size_t)bh * NSEQ + c * CHK + s) * FF + fg * 8];
    int sw = (fg & 15) << 3;
#pragma unroll
    for (int j = 0; j < 8; ++j)
      kt[fg * 8 + j][s ^ sw] = kv[j];
  }
  __syncthreads();
  int lane = tid & 63, wv = tid >> 6, lr = lane & 15, lq = lane >> 4;
  int wmd = wv & 1, wnf = wv >> 1;
  f32x4 acc[4][4] = {};
#pragma unroll
  for (int ks = 0; ks < 4; ++ks) {
    f16x8 av[4];
#pragma unroll
    for (int im = 0; im < 4; ++im)
      av[im] = *(const f16x8*)&vt[wmd * 64 + im * 16 + lr][ks * 32 + lq * 8];
#pragma unroll
    for (int fn = 0; fn < 4; ++fn) {
      int F = wnf * 64 + fn * 16 + lr;
      f16x8 bv = *(const f16x8*)&kt[F][(ks * 32 + lq * 8) ^ (((F >> 3) & 15) << 3)];
#pragma unroll
      for (int im = 0; im < 4; ++im) acc[im][fn] = MFMA16(av[im], bv, acc[im][fn]);
    }
  }
  _Float16* Sp = S + ((size_t)bh * NC + c) * (size_t)(DD * FF);
#pragma unroll
  for (int im = 0; im < 4; ++im)
#pragma unroll
    for (int fn = 0; fn < 4; ++fn) {
      int f = wnf * 64 + fn * 16 + lr;
#pragma unroll
      for (int r = 0; r < 4; ++r) {
        int d = wmd * 64 + im * 16 + lq * 4 + r;
        Sp[(size_t)d * FF + f] = (_Float16)acc[im][fn][r];
      }
    }
}

// ---------------- k3: prefix->Wf, suffix in-place over S (becomes Wr) ------
__global__ void prefix_kernel(_Float16* S_Wr, _Float16* __restrict__ Wf) {
  size_t idx = (size_t)blockIdx.x * 256 + threadIdx.x;
  int bh = (int)(idx >> 15);
  int df = (int)(idx & 32767);
  size_t base = (size_t)bh * NC * 32768 + df;
  float vals[NC];
#pragma unroll
  for (int c = 0; c < NC; ++c) vals[c] = (float)S_Wr[base + (size_t)c * 32768];
  float run = 0.f;
#pragma unroll
  for (int c = 0; c < NC; ++c) { Wf[base + (size_t)c * 32768] = (_Float16)run; run += vals[c]; }
  run = 0.f;
#pragma unroll
  for (int c = NC - 1; c >= 0; --c) { S_Wr[base + (size_t)c * 32768] = (_Float16)run; run += vals[c]; }
}

// ---------------- k4: fused phase-2 scan (full chunk per block) ----------------
__global__ __launch_bounds__(512, 2)
void scan_kernel(const _Float16* __restrict__ qp, const _Float16* __restrict__ kp,
                 const _Float16* __restrict__ vT, const _Float16* __restrict__ Wf,
                 const _Float16* __restrict__ Wr, float* __restrict__ out) {
  __shared__ __align__(16) _Float16 vt[128][136];
  __shared__ __align__(16) _Float16 P[128][136];
  int blk = blockIdx.x;
  int c = blk & 31, bh = blk >> 5;
  const _Float16* qpc = qp + ((size_t)bh * NSEQ + c * CHK) * FF;
  const _Float16* kpc = kp + ((size_t)bh * NSEQ + c * CHK) * FF;
  int tid = threadIdx.x, lane = tid & 63, wv = tid >> 6, lr = lane & 15, lq = lane >> 4;
  int wm = wv & 3, wn = wv >> 2;  // wm: 4x32 rows; wn: 2x64 (s-half in A, d-half in B)

  // aq: 16 frags (reused by phase A and inter), batched but bounded
  f16x8 aq[2][8];
#pragma unroll
  for (int im = 0; im < 2; ++im)
#pragma unroll
    for (int ks = 0; ks < 8; ++ks)
      aq[im][ks] = *(const f16x8*)&qpc[(size_t)(wm * 32 + im * 16 + lr) * FF + ks * 32 + lq * 8];
  // stage vt (b128, conflict-free)
#pragma unroll
  for (int it = 0; it < 4; ++it) {
    int flat = it * 512 + tid;
    int d = flat >> 4, sg = flat & 15;
    *(f16x8*)&vt[d][sg * 8] = *(const f16x8*)&vT[((size_t)bh * DD + d) * NSEQ + c * CHK + sg * 8];
  }
  // Phase A: P = qp.kp^T with bk double-buffer over j
  f16x8 bk[2][8];
#pragma unroll
  for (int ks = 0; ks < 8; ++ks)
    bk[0][ks] = *(const f16x8*)&kpc[(size_t)(wn * 64 + lr) * FF + ks * 32 + lq * 8];
  f32x4 pacc[2][4] = {};
#pragma unroll
  for (int j = 0; j < 4; ++j) {
    int cur = j & 1;
    if (j < 3)
#pragma unroll
      for (int ks = 0; ks < 8; ++ks)
        bk[cur ^ 1][ks] = *(const f16x8*)&kpc[(size_t)(wn * 64 + (j + 1) * 16 + lr) * FF + ks * 32 + lq * 8];
#pragma unroll
    for (int ks = 0; ks < 8; ++ks)
#pragma unroll
      for (int im = 0; im < 2; ++im)
        pacc[im][j] = MFMA16(aq[im][ks], bk[cur][ks], pacc[im][j]);
  }
#pragma unroll
  for (int im = 0; im < 2; ++im)
#pragma unroll
    for (int j = 0; j < 4; ++j)
#pragma unroll
      for (int r = 0; r < 4; ++r)
        P[wm * 32 + im * 16 + lq * 4 + r][wn * 64 + j * 16 + lr] = (_Float16)pacc[im][j][r];

  // prefetch W frags for jd=0 (before barrier: overlaps P writes)
  const _Float16* Wfc = Wf + ((size_t)bh * NC + c) * (size_t)(DD * FF);
  const _Float16* Wrc = Wr + ((size_t)bh * NC + c) * (size_t)(DD * FF);
  f16x8 bf[8], br[8];
#pragma unroll
  for (int ks = 0; ks < 8; ++ks) {
    int d = wn * 64 + lr;
    bf[ks] = *(const f16x8*)&Wfc[(size_t)d * FF + ks * 32 + lq * 8];
    br[ks] = *(const f16x8*)&Wrc[(size_t)d * FF + ks * 32 + lq * 8];
  }
  __syncthreads();

  // Phase B: inter (q.W) per d-group; W prefetch 1 group ahead; intra interleaved
  f32x4 af[2][4] = {}, ar[2][4] = {};
#pragma unroll
  for (int jd = 0; jd < 4; ++jd) {
#pragma unroll
    for (int ks = 0; ks < 8; ++ks)
#pragma unroll
      for (int im = 0; im < 2; ++im) {
        af[im][jd] = MFMA16(aq[im][ks], bf[ks], af[im][jd]);
        ar[im][jd] = MFMA16(aq[im][ks], br[ks], ar[im][jd]);
      }
    if (jd < 3)
#pragma unroll
      for (int ks = 0; ks < 8; ++ks) {
        int d = wn * 64 + (jd + 1) * 16 + lr;
        bf[ks] = *(const f16x8*)&Wfc[(size_t)d * FF + ks * 32 + lq * 8];
        br[ks] = *(const f16x8*)&Wrc[(size_t)d * FF + ks * 32 + lq * 8];
      }
    // intra k-step ks=jd (LDS-only; covers W prefetch latency)
    {
      int ks = jd;
      f16x8 bv[4];
#pragma unroll
      for (int jd2 = 0; jd2 < 4; ++jd2)
        bv[jd2] = *(const f16x8*)&vt[wn * 64 + jd2 * 16 + lr][ks * 32 + lq * 8];
#pragma unroll
      for (int im = 0; im < 2; ++im) {
        int irow = wm * 32 + im * 16 + lr;
        f16x8 p = *(const f16x8*)&P[irow][ks * 32 + lq * 8];
        f16x8 pf = p, pr = p;
#pragma unroll
        for (int jj = 0; jj < 8; ++jj) {
          int s = ks * 32 + lq * 8 + jj;
          pf[jj] = (s <= irow) ? p[jj] : (_Float16)0.0f;
          pr[jj] = (s >= irow) ? p[jj] : (_Float16)0.0f;
        }
#pragma unroll
        for (int jd2 = 0; jd2 < 4; ++jd2) {
          af[im][jd2] = MFMA16(pf, bv[jd2], af[im][jd2]);
          ar[im][jd2] = MFMA16(pr, bv[jd2], ar[im][jd2]);
        }
      }
    }
  }

  // epilogue
  float* oc = out + ((size_t)bh * NSEQ + c * CHK) * DD;
#pragma unroll
  for (int im = 0; im < 2; ++im)
#pragma unroll
    for (int jd = 0; jd < 4; ++jd) {
      int d = wn * 64 + jd * 16 + lr;
#pragma unroll
      for (int r = 0; r < 4; ++r) {
        int il = wm * 32 + im * 16 + lq * 4 + r;
        int gi = c * CHK + il;
        oc[(size_t)il * DD + d] = af[im][jd][r] / (float)(gi + 1) + ar[im][jd][r] / (float)(NSEQ - gi);
      }
    }
}

// ---------------- launcher ----------------
extern "C" void kernel_launch(void* const* d_in, const int* in_sizes, int n_in,
                              void* d_out, int out_size, void* d_ws, size_t ws_size,
                              hipStream_t stream) {
  const float* q  = (const float*)d_in[0];
  const float* k  = (const float*)d_in[1];
  const float* v  = (const float*)d_in[2];
  const float* w1 = (const float*)d_in[3];
  const float* b1 = (const float*)d_in[4];
  const float* w2 = (const float*)d_in[5];
  const float* b2 = (const float*)d_in[6];
  float* out = (float*)d_out;

  char* ws = (char*)d_ws;
  const size_t SZ = 50331648ull;  // 24*4096*256*2B
  _Float16* w1h = (_Float16*)(ws);
  _Float16* w2h = (_Float16*)(ws + 65536);
  _Float16* qp  = (_Float16*)(ws + 196608);
  _Float16* kp  = (_Float16*)(ws + 196608 + SZ);
  _Float16* Wf  = (_Float16*)(ws + 196608 + 2 * SZ);
  _Float16* S   = (_Float16*)(ws + 196608 + 3 * SZ);  // reused in-place as Wr
  _Float16* vT  = (_Float16*)(ws + 196608 + 4 * SZ);  // 24MB
  _Float16* Wr  = S;
  _Float16* h   = Wf;  // h spans Wf+S regions: 2*SZ = 100663296 B = 196608*256*2B exactly

  prep_kernel<<<dim3(256), dim3(256), 0, stream>>>(w1, w2, w1h, w2h);
  vt_kernel<<<dim3(BH * NC), dim3(256), 0, stream>>>(v, vT);
  gemm1_kernel<<<dim3(256), dim3(1024), 0, stream>>>(q, k, b1, w1h, h);
  gemm2_kernel<<<dim3(256), dim3(1024), 0, stream>>>(h, b2, w2h, qp, kp);
  s_kernel<<<dim3(BH * NC), dim3(512), 0, stream>>>(vT, kp, S);
  prefix_kernel<<<dim3(BH * DD * FF / 256), dim3(256), 0, stream>>>(S, Wf);
  scan_kernel<<<dim3(BH * NC), dim3(512), 0, stream>>>(qp, kp, vT, Wf, Wr, out);
}

// Round 10
// 396.092 us; speedup vs baseline: 1.4422x; 1.4422x over previous
//
#include <hip/hip_runtime.h>

// TTRFluxLayer R11b: identical to R11 (container infra failed twice; re-run).
// phi = R4's kernel (128.7us measured: 1024thr, LDS-staged weights, both w2
//       K-panels preloaded to regs at top, LDS epilogue) MINUS the kpT/ot
//       transpose epilogue (s_kernel has done the kp transpose in LDS since R7).
//       Removes 48MB HBM write + 2 barrier phases + ~3.2M bank conflicts.
// R10 post-mortem: h round-trip through HBM = 590MB FETCH (L2 thrash, 4-way
// re-read redundancy) + 282MB WRITE (partial-line RMW) -> never again.
// Fixed rest-of-pipeline = 273.5us across rounds; scan_kernel never profiled —
// with phi ~110us it should surface in top-5 for the next round.
// ws: w1h 64K | w2h 128K | qp 48M | kp 48M | Wf 48M | S/Wr 48M | vT 24M

typedef __attribute__((ext_vector_type(8))) _Float16 f16x8;
typedef __attribute__((ext_vector_type(4))) _Float16 f16x4;
typedef __attribute__((ext_vector_type(4))) float f32x4;

#define MFMA16(a, b, c) __builtin_amdgcn_mfma_f32_16x16x32_f16((a), (b), (c), 0, 0, 0)

constexpr int BH   = 24;
constexpr int NSEQ = 4096;
constexpr int DD   = 128;
constexpr int FF   = 256;
constexpr int CHK  = 128;
constexpr int NC   = NSEQ / CHK;     // 32
constexpr int NROWS = BH * NSEQ;     // 98304

// ---------------- k0: weight convert ----------------
__global__ void prep_kernel(const float* __restrict__ w1, const float* __restrict__ w2,
                            _Float16* __restrict__ w1h, _Float16* __restrict__ w2h) {
  int i = blockIdx.x * 256 + threadIdx.x;
  if (i < FF * DD) w1h[i] = (_Float16)w1[i];
  if (i < FF * FF) w2h[i] = (_Float16)w2[i];
}

// ---------------- k0b: v -> vT fp16 [bh][d][s] ----------------
__global__ void vt_kernel(const float* __restrict__ v, _Float16* __restrict__ vT) {
  __shared__ __align__(16) _Float16 lt[128][136];
  int blk = blockIdx.x;
  int c = blk & 31, bh = blk >> 5;
  const float* vc = v + ((size_t)bh * NSEQ + c * CHK) * DD;
  int tid = threadIdx.x;
#pragma unroll
  for (int it = 0; it < 16; ++it) {
    int flat = it * 1024 + tid * 4;  // 128s x 128d
    int s = flat >> 7, d0 = flat & 127;
    float4 xv = *(const float4*)&vc[(size_t)s * DD + d0];
    lt[d0 + 0][s] = (_Float16)xv.x;
    lt[d0 + 1][s] = (_Float16)xv.y;
    lt[d0 + 2][s] = (_Float16)xv.z;
    lt[d0 + 3][s] = (_Float16)xv.w;
  }
  __syncthreads();
#pragma unroll
  for (int it = 0; it < 8; ++it) {
    int flat = it * 256 + tid;  // 128d x 16 s-groups
    int d = flat >> 4, sg = flat & 15;
    *(f16x8*)&vT[((size_t)bh * DD + d) * NSEQ + c * CHK + sg * 8] =
        *(const f16x8*)&lt[d][sg * 8];
  }
}

// ---------------- k1: phi (R4 structure, kpT epilogue removed) ----------------
__global__ __launch_bounds__(1024, 4)
void phi_kernel(const float* __restrict__ q, const float* __restrict__ k,
                const float* __restrict__ b1, const float* __restrict__ b2,
                const _Float16* __restrict__ w1h, const _Float16* __restrict__ w2h,
                _Float16* __restrict__ qp, _Float16* __restrict__ kp) {
  __shared__ __align__(16) char smem[137216];
  _Float16 (*xs)[136]  = (_Float16(*)[136])smem;             // [128][136] phase1
  _Float16 (*w1s)[136] = (_Float16(*)[136])(smem + 34816);   // [256][136] phase1
  _Float16 (*hs)[264]  = (_Float16(*)[264])smem;             // [128][264] phase2+
  _Float16 (*w2s)[136] = (_Float16(*)[136])(smem + 67584);   // [256][136] K-panel
  _Float16 (*os)[264]  = (_Float16(*)[264])smem;             // [128][264] epi (alias hs)
  int blk = blockIdx.x;
  const float* src;
  _Float16* dst;
  int rb;
  if (blk < NROWS / 128) { src = q; dst = qp; rb = blk * 128; }
  else                   { src = k; dst = kp; rb = (blk - NROWS / 128) * 128; }
  int tid = threadIdx.x;
  int lane = tid & 63, wv = tid >> 6, lr = lane & 15, lq = lane >> 4;
  int wm = wv & 3, wn = wv >> 2;  // 4 row-strips(32) x 4 F-strips(64)

  // T14: issue BOTH w2 K-panels to regs now; latency hides under staging+GEMM1.
  f16x8 p0r[4], p1r[4];
#pragma unroll
  for (int it = 0; it < 4; ++it) {
    int flat = it * 1024 + tid;
    int g = flat >> 4, cg = flat & 15;
    p0r[it] = *(const f16x8*)&w2h[(size_t)g * FF + cg * 8];
    p1r[it] = *(const f16x8*)&w2h[(size_t)g * FF + 128 + cg * 8];
  }
  // stage w1 (256x128) and x (128x128 f32->f16)
#pragma unroll
  for (int it = 0; it < 4; ++it) {
    int flat = it * 1024 + tid;
    int f = flat >> 4, cg = flat & 15;
    *(f16x8*)&w1s[f][cg * 8] = *(const f16x8*)&w1h[f * DD + cg * 8];
  }
#pragma unroll
  for (int it = 0; it < 4; ++it) {
    int flat = it * 1024 + tid;
    int r = flat >> 5, dg = flat & 31;
    float4 xv = *(const float4*)&src[(size_t)(rb + r) * DD + dg * 4];
    f16x4 hv = {(_Float16)xv.x, (_Float16)xv.y, (_Float16)xv.z, (_Float16)xv.w};
    *(f16x4*)&xs[r][dg * 4] = hv;
  }
  __syncthreads();

  // GEMM1: wave tile 32x64 over 128x256
  f32x4 acc[2][4] = {};
#pragma unroll
  for (int ks = 0; ks < 4; ++ks) {
    f16x8 av[2];
#pragma unroll
    for (int im = 0; im < 2; ++im)
      av[im] = *(const f16x8*)&xs[wm * 32 + im * 16 + lr][ks * 32 + lq * 8];
#pragma unroll
    for (int fn = 0; fn < 4; ++fn) {
      f16x8 bv = *(const f16x8*)&w1s[wn * 64 + fn * 16 + lr][ks * 32 + lq * 8];
#pragma unroll
      for (int im = 0; im < 2; ++im) acc[im][fn] = MFMA16(av[im], bv, acc[im][fn]);
    }
  }
  __syncthreads();  // xs/w1s dead

  // w2 panel0 regs -> LDS (no global latency here) + hs = silu(acc+b1)
#pragma unroll
  for (int it = 0; it < 4; ++it) {
    int flat = it * 1024 + tid;
    int g = flat >> 4, cg = flat & 15;
    *(f16x8*)&w2s[g][cg * 8] = p0r[it];
  }
#pragma unroll
  for (int im = 0; im < 2; ++im)
#pragma unroll
    for (int fn = 0; fn < 4; ++fn) {
      int f = wn * 64 + fn * 16 + lr;
      float bb = b1[f];
      int r0 = wm * 32 + im * 16 + lq * 4;
#pragma unroll
      for (int r = 0; r < 4; ++r) {
        float xv = acc[im][fn][r] + bb;
        hs[r0 + r][f] = (_Float16)(xv / (1.0f + __expf(-xv)));
      }
    }
  __syncthreads();

  // GEMM2 K-panel 0
  f32x4 ac2[2][4] = {};
#pragma unroll
  for (int ks = 0; ks < 4; ++ks) {
    f16x8 av[2];
#pragma unroll
    for (int im = 0; im < 2; ++im)
      av[im] = *(const f16x8*)&hs[wm * 32 + im * 16 + lr][ks * 32 + lq * 8];
#pragma unroll
    for (int fn = 0; fn < 4; ++fn) {
      f16x8 bv = *(const f16x8*)&w2s[wn * 64 + fn * 16 + lr][ks * 32 + lq * 8];
#pragma unroll
      for (int im = 0; im < 2; ++im) ac2[im][fn] = MFMA16(av[im], bv, ac2[im][fn]);
    }
  }
  __syncthreads();  // panel0 consumed
#pragma unroll
  for (int it = 0; it < 4; ++it) {
    int flat = it * 1024 + tid;
    int g = flat >> 4, cg = flat & 15;
    *(f16x8*)&w2s[g][cg * 8] = p1r[it];
  }
  __syncthreads();
  // GEMM2 K-panel 1
#pragma unroll
  for (int ks = 0; ks < 4; ++ks) {
    f16x8 av[2];
#pragma unroll
    for (int im = 0; im < 2; ++im)
      av[im] = *(const f16x8*)&hs[wm * 32 + im * 16 + lr][128 + ks * 32 + lq * 8];
#pragma unroll
    for (int fn = 0; fn < 4; ++fn) {
      f16x8 bv = *(const f16x8*)&w2s[wn * 64 + fn * 16 + lr][ks * 32 + lq * 8];
#pragma unroll
      for (int im = 0; im < 2; ++im) ac2[im][fn] = MFMA16(av[im], bv, ac2[im][fn]);
    }
  }
  __syncthreads();  // hs/w2s dead -> epilogue may alias

  // epilogue: stage out tile in LDS, then coalesced f16x8 stores (qp/kp only)
#pragma unroll
  for (int im = 0; im < 2; ++im)
#pragma unroll
    for (int fn = 0; fn < 4; ++fn) {
      int g = wn * 64 + fn * 16 + lr;
      float bb = b2[g];
      int r0 = wm * 32 + im * 16 + lq * 4;
#pragma unroll
      for (int r = 0; r < 4; ++r)
        os[r0 + r][g] = (_Float16)(ac2[im][fn][r] + bb);
    }
  __syncthreads();
#pragma unroll
  for (int it = 0; it < 4; ++it) {
    int flat = it * 1024 + tid;
    int r = flat >> 5, cg = flat & 31;
    *(f16x8*)&dst[(size_t)(rb + r) * FF + cg * 8] = *(const f16x8*)&os[r][cg * 8];
  }
}

// ---------------- k2: S^T[d][f] per chunk (kp transposed in LDS) ----------------
__global__ __launch_bounds__(512, 2)
void s_kernel(const _Float16* __restrict__ vT, const _Float16* __restrict__ kp,
              _Float16* __restrict__ S) {
  __shared__ __align__(16) _Float16 vt[128][136];
  __shared__ __align__(16) _Float16 kt[256][136];  // kt[f][s ^ swz(f)]
  int blk = blockIdx.x;
  int c = blk & 31, bh = blk >> 5;
  int tid = threadIdx.x;
#pragma unroll
  for (int it = 0; it < 4; ++it) {
    int flat = it * 512 + tid;
    int d = flat >> 4, sg = flat & 15;
    *(f16x8*)&vt[d][sg * 8] = *(const f16x8*)&vT[((size_t)bh * DD + d) * NSEQ + c * CHK + sg * 8];
  }
#pragma unroll
  for (int it = 0; it < 8; ++it) {
    int flat = it * 512 + tid;  // 128 s x 32 f-groups
    int s = flat >> 5, fg = flat & 31;
    f16x8 kv = *(const f16x8*)&kp[((size_t)bh * NSEQ + c * CHK + s) * FF + fg * 8];
    int sw = (fg & 15) << 3;
#pragma unroll
    for (int j = 0; j < 8; ++j)
      kt[fg * 8 + j][s ^ sw] = kv[j];
  }
  __syncthreads();
  int lane = tid & 63, wv = tid >> 6, lr = lane & 15, lq = lane >> 4;
  int wmd = wv & 1, wnf = wv >> 1;
  f32x4 acc[4][4] = {};
#pragma unroll
  for (int ks = 0; ks < 4; ++ks) {
    f16x8 av[4];
#pragma unroll
    for (int im = 0; im < 4; ++im)
      av[im] = *(const f16x8*)&vt[wmd * 64 + im * 16 + lr][ks * 32 + lq * 8];
#pragma unroll
    for (int fn = 0; fn < 4; ++fn) {
      int F = wnf * 64 + fn * 16 + lr;
      f16x8 bv = *(const f16x8*)&kt[F][(ks * 32 + lq * 8) ^ (((F >> 3) & 15) << 3)];
#pragma unroll
      for (int im = 0; im < 4; ++im) acc[im][fn] = MFMA16(av[im], bv, acc[im][fn]);
    }
  }
  _Float16* Sp = S + ((size_t)bh * NC + c) * (size_t)(DD * FF);
#pragma unroll
  for (int im = 0; im < 4; ++im)
#pragma unroll
    for (int fn = 0; fn < 4; ++fn) {
      int f = wnf * 64 + fn * 16 + lr;
#pragma unroll
      for (int r = 0; r < 4; ++r) {
        int d = wmd * 64 + im * 16 + lq * 4 + r;
        Sp[(size_t)d * FF + f] = (_Float16)acc[im][fn][r];
      }
    }
}

// ---------------- k3: prefix->Wf, suffix in-place over S (becomes Wr) ------
__global__ void prefix_kernel(_Float16* S_Wr, _Float16* __restrict__ Wf) {
  size_t idx = (size_t)blockIdx.x * 256 + threadIdx.x;
  int bh = (int)(idx >> 15);
  int df = (int)(idx & 32767);
  size_t base = (size_t)bh * NC * 32768 + df;
  float vals[NC];
#pragma unroll
  for (int c = 0; c < NC; ++c) vals[c] = (float)S_Wr[base + (size_t)c * 32768];
  float run = 0.f;
#pragma unroll
  for (int c = 0; c < NC; ++c) { Wf[base + (size_t)c * 32768] = (_Float16)run; run += vals[c]; }
  run = 0.f;
#pragma unroll
  for (int c = NC - 1; c >= 0; --c) { S_Wr[base + (size_t)c * 32768] = (_Float16)run; run += vals[c]; }
}

// ---------------- k4: fused phase-2 scan (full chunk per block) ----------------
__global__ __launch_bounds__(512, 2)
void scan_kernel(const _Float16* __restrict__ qp, const _Float16* __restrict__ kp,
                 const _Float16* __restrict__ vT, const _Float16* __restrict__ Wf,
                 const _Float16* __restrict__ Wr, float* __restrict__ out) {
  __shared__ __align__(16) _Float16 vt[128][136];
  __shared__ __align__(16) _Float16 P[128][136];
  int blk = blockIdx.x;
  int c = blk & 31, bh = blk >> 5;
  const _Float16* qpc = qp + ((size_t)bh * NSEQ + c * CHK) * FF;
  const _Float16* kpc = kp + ((size_t)bh * NSEQ + c * CHK) * FF;
  int tid = threadIdx.x, lane = tid & 63, wv = tid >> 6, lr = lane & 15, lq = lane >> 4;
  int wm = wv & 3, wn = wv >> 2;  // wm: 4x32 rows; wn: 2x64 (s-half in A, d-half in B)

  // aq: 16 frags (reused by phase A and inter), batched but bounded
  f16x8 aq[2][8];
#pragma unroll
  for (int im = 0; im < 2; ++im)
#pragma unroll
    for (int ks = 0; ks < 8; ++ks)
      aq[im][ks] = *(const f16x8*)&qpc[(size_t)(wm * 32 + im * 16 + lr) * FF + ks * 32 + lq * 8];
  // stage vt (b128, conflict-free)
#pragma unroll
  for (int it = 0; it < 4; ++it) {
    int flat = it * 512 + tid;
    int d = flat >> 4, sg = flat & 15;
    *(f16x8*)&vt[d][sg * 8] = *(const f16x8*)&vT[((size_t)bh * DD + d) * NSEQ + c * CHK + sg * 8];
  }
  // Phase A: P = qp.kp^T with bk double-buffer over j
  f16x8 bk[2][8];
#pragma unroll
  for (int ks = 0; ks < 8; ++ks)
    bk[0][ks] = *(const f16x8*)&kpc[(size_t)(wn * 64 + lr) * FF + ks * 32 + lq * 8];
  f32x4 pacc[2][4] = {};
#pragma unroll
  for (int j = 0; j < 4; ++j) {
    int cur = j & 1;
    if (j < 3)
#pragma unroll
      for (int ks = 0; ks < 8; ++ks)
        bk[cur ^ 1][ks] = *(const f16x8*)&kpc[(size_t)(wn * 64 + (j + 1) * 16 + lr) * FF + ks * 32 + lq * 8];
#pragma unroll
    for (int ks = 0; ks < 8; ++ks)
#pragma unroll
      for (int im = 0; im < 2; ++im)
        pacc[im][j] = MFMA16(aq[im][ks], bk[cur][ks], pacc[im][j]);
  }
#pragma unroll
  for (int im = 0; im < 2; ++im)
#pragma unroll
    for (int j = 0; j < 4; ++j)
#pragma unroll
      for (int r = 0; r < 4; ++r)
        P[wm * 32 + im * 16 + lq * 4 + r][wn * 64 + j * 16 + lr] = (_Float16)pacc[im][j][r];

  // prefetch W frags for jd=0 (before barrier: overlaps P writes)
  const _Float16* Wfc = Wf + ((size_t)bh * NC + c) * (size_t)(DD * FF);
  const _Float16* Wrc = Wr + ((size_t)bh * NC + c) * (size_t)(DD * FF);
  f16x8 bf[8], br[8];
#pragma unroll
  for (int ks = 0; ks < 8; ++ks) {
    int d = wn * 64 + lr;
    bf[ks] = *(const f16x8*)&Wfc[(size_t)d * FF + ks * 32 + lq * 8];
    br[ks] = *(const f16x8*)&Wrc[(size_t)d * FF + ks * 32 + lq * 8];
  }
  __syncthreads();

  // Phase B: inter (q.W) per d-group; W prefetch 1 group ahead; intra interleaved
  f32x4 af[2][4] = {}, ar[2][4] = {};
#pragma unroll
  for (int jd = 0; jd < 4; ++jd) {
#pragma unroll
    for (int ks = 0; ks < 8; ++ks)
#pragma unroll
      for (int im = 0; im < 2; ++im) {
        af[im][jd] = MFMA16(aq[im][ks], bf[ks], af[im][jd]);
        ar[im][jd] = MFMA16(aq[im][ks], br[ks], ar[im][jd]);
      }
    if (jd < 3)
#pragma unroll
      for (int ks = 0; ks < 8; ++ks) {
        int d = wn * 64 + (jd + 1) * 16 + lr;
        bf[ks] = *(const f16x8*)&Wfc[(size_t)d * FF + ks * 32 + lq * 8];
        br[ks] = *(const f16x8*)&Wrc[(size_t)d * FF + ks * 32 + lq * 8];
      }
    // intra k-step ks=jd (LDS-only; covers W prefetch latency)
    {
      int ks = jd;
      f16x8 bv[4];
#pragma unroll
      for (int jd2 = 0; jd2 < 4; ++jd2)
        bv[jd2] = *(const f16x8*)&vt[wn * 64 + jd2 * 16 + lr][ks * 32 + lq * 8];
#pragma unroll
      for (int im = 0; im < 2; ++im) {
        int irow = wm * 32 + im * 16 + lr;
        f16x8 p = *(const f16x8*)&P[irow][ks * 32 + lq * 8];
        f16x8 pf = p, pr = p;
#pragma unroll
        for (int jj = 0; jj < 8; ++jj) {
          int s = ks * 32 + lq * 8 + jj;
          pf[jj] = (s <= irow) ? p[jj] : (_Float16)0.0f;
          pr[jj] = (s >= irow) ? p[jj] : (_Float16)0.0f;
        }
#pragma unroll
        for (int jd2 = 0; jd2 < 4; ++jd2) {
          af[im][jd2] = MFMA16(pf, bv[jd2], af[im][jd2]);
          ar[im][jd2] = MFMA16(pr, bv[jd2], ar[im][jd2]);
        }
      }
    }
  }

  // epilogue
  float* oc = out + ((size_t)bh * NSEQ + c * CHK) * DD;
#pragma unroll
  for (int im = 0; im < 2; ++im)
#pragma unroll
    for (int jd = 0; jd < 4; ++jd) {
      int d = wn * 64 + jd * 16 + lr;
#pragma unroll
      for (int r = 0; r < 4; ++r) {
        int il = wm * 32 + im * 16 + lq * 4 + r;
        int gi = c * CHK + il;
        oc[(size_t)il * DD + d] = af[im][jd][r] / (float)(gi + 1) + ar[im][jd][r] / (float)(NSEQ - gi);
      }
    }
}

// ---------------- launcher ----------------
extern "C" void kernel_launch(void* const* d_in, const int* in_sizes, int n_in,
                              void* d_out, int out_size, void* d_ws, size_t ws_size,
                              hipStream_t stream) {
  const float* q  = (const float*)d_in[0];
  const float* k  = (const float*)d_in[1];
  const float* v  = (const float*)d_in[2];
  const float* w1 = (const float*)d_in[3];
  const float* b1 = (const float*)d_in[4];
  const float* w2 = (const float*)d_in[5];
  const float* b2 = (const float*)d_in[6];
  float* out = (float*)d_out;

  char* ws = (char*)d_ws;
  const size_t SZ = 50331648ull;  // 24*4096*256*2B
  _Float16* w1h = (_Float16*)(ws);
  _Float16* w2h = (_Float16*)(ws + 65536);
  _Float16* qp  = (_Float16*)(ws + 196608);
  _Float16* kp  = (_Float16*)(ws + 196608 + SZ);
  _Float16* Wf  = (_Float16*)(ws + 196608 + 2 * SZ);
  _Float16* S   = (_Float16*)(ws + 196608 + 3 * SZ);  // reused in-place as Wr
  _Float16* vT  = (_Float16*)(ws + 196608 + 4 * SZ);  // 24MB
  _Float16* Wr  = S;

  prep_kernel<<<dim3(256), dim3(256), 0, stream>>>(w1, w2, w1h, w2h);
  vt_kernel<<<dim3(BH * NC), dim3(256), 0, stream>>>(v, vT);
  phi_kernel<<<dim3(2 * NROWS / 128), dim3(1024), 0, stream>>>(q, k, b1, b2, w1h, w2h, qp, kp);
  s_kernel<<<dim3(BH * NC), dim3(512), 0, stream>>>(vT, kp, S);
  prefix_kernel<<<dim3(BH * DD * FF / 256), dim3(256), 0, stream>>>(S, Wf);
  scan_kernel<<<dim3(BH * NC), dim3(512), 0, stream>>>(qp, kp, vT, Wf, Wr, out);
}